// Round 2
// baseline (2712.226 us; speedup 1.0000x reference)
//
#include <hip/hip_runtime.h>
#include <math.h>

#define B_   16
#define L_   8192
#define D_   64
#define R_   4
#define NB_  128   // n_buckets = L/64
#define NH_  64    // rand_matrix last dim = n_buckets/2

// ---------------- K1: normalize rand_matrix columns over d (fp64), store [b][r][n][d]
__global__ __launch_bounds__(64) void k_rmnorm(const float* __restrict__ rm, double* __restrict__ rmn) {
    int b = blockIdx.x >> 2, r = blockIdx.x & 3;
    int n = threadIdx.x;
    float v[D_];
    double ss = 0.0;
    #pragma unroll
    for (int d = 0; d < D_; ++d) {
        float f = rm[((size_t)(b * D_ + d) * R_ + r) * NH_ + n];
        v[d] = f;
        ss += (double)f * (double)f;
    }
    double nrm = sqrt(ss); if (nrm < 1e-12) nrm = 1e-12;
    double inv = 1.0 / nrm;
    double* o = rmn + ((size_t)(b * R_ + r) * NH_ + n) * D_;
    #pragma unroll
    for (int d = 0; d < D_; ++d) o[d] = (double)v[d] * inv;
}

// ---------------- K2: LSH hash, fp64 dots (argmax over [xR,-xR]); also 1/||q||
__global__ __launch_bounds__(256) void k_hash(const float* __restrict__ q, const double* __restrict__ rmn,
                                              float* __restrict__ rn, int* __restrict__ h) {
    __shared__ double rms[NH_ * D_]; // 32 KB
    int b = blockIdx.z, r = blockIdx.y;
    int l = blockIdx.x * 256 + threadIdx.x;
    const double* src = rmn + (size_t)(b * R_ + r) * NH_ * D_;
    for (int i = threadIdx.x; i < NH_ * D_; i += 256) rms[i] = src[i];
    const float* qp = q + ((size_t)b * L_ + l) * D_;
    double qd[D_];
    double ss = 0.0;
    #pragma unroll
    for (int d = 0; d < D_; d += 4) {
        float4 f = *(const float4*)(qp + d);
        qd[d] = f.x; qd[d+1] = f.y; qd[d+2] = f.z; qd[d+3] = f.w;
        ss += (double)f.x * f.x + (double)f.y * f.y + (double)f.z * f.z + (double)f.w * f.w;
    }
    __syncthreads();
    double best = -1.0e300; int bi = 0;
    for (int n = 0; n < NH_; ++n) {
        const double* kp = &rms[n * D_];
        double a0 = 0, a1 = 0, a2 = 0, a3 = 0;
        #pragma unroll
        for (int d = 0; d < D_; d += 4) {
            a0 = fma(qd[d],   kp[d],   a0);
            a1 = fma(qd[d+1], kp[d+1], a1);
            a2 = fma(qd[d+2], kp[d+2], a2);
            a3 = fma(qd[d+3], kp[d+3], a3);
        }
        double s = (a0 + a1) + (a2 + a3);
        if (s > best)  { best = s;  bi = n; }        // +xR first (ref concat order)
        if (-s > best) { best = -s; bi = n + NH_; }  // then -xR
    }
    h[(size_t)(b * R_ + r) * L_ + l] = bi;
    if (r == 0) {
        double nrm = sqrt(ss); if (nrm < 1e-12) nrm = 1e-12;
        rn[(size_t)b * L_ + l] = (float)(1.0 / nrm);
    }
}

// ---------------- K3: stable counting sort by bucket per (b,r); 1 wave per block
//                  also emits inverse permutation iv[l] = sorted position of l
__global__ __launch_bounds__(64) void k_sort(const int* __restrict__ h, int* __restrict__ idx,
                                             int* __restrict__ sb, int* __restrict__ iv) {
    __shared__ unsigned int cnt[NB_ * 64]; // [bucket][thread], 32 KB
    int br = blockIdx.x;
    const int* hh = h + (size_t)br * L_;
    int t = threadIdx.x;
    for (int i = t; i < NB_ * 64; i += 64) cnt[i] = 0;
    __syncthreads();
    int base = t * 128;                      // each thread owns 128 consecutive l
    for (int i = 0; i < 128; ++i) { int bk = hh[base + i]; cnt[bk * 64 + t]++; }
    __syncthreads();
    int fb = t * 128;
    unsigned int local = 0;
    for (int i = 0; i < 128; ++i) local += cnt[fb + i];
    unsigned int v = local;
    #pragma unroll
    for (int off = 1; off < 64; off <<= 1) {
        unsigned int u = __shfl_up(v, off);
        if (t >= off) v += u;
    }
    unsigned int run = v - local; // exclusive base for this thread's 128 cells
    for (int i = 0; i < 128; ++i) { unsigned int c0 = cnt[fb + i]; cnt[fb + i] = run; run += c0; }
    __syncthreads();
    int* oi = idx + (size_t)br * L_;
    int* ob = sb  + (size_t)br * L_;
    int* ivp = iv + (size_t)br * L_;
    for (int i = 0; i < 128; ++i) {
        int l = base + i; int bk = hh[l];
        unsigned int pos = cnt[bk * 64 + t]++;
        oi[pos] = l; ob[pos] = bk; ivp[l] = (int)pos;
    }
}

// ---------------- K4: pass 1 — lse per sorted position.
// Block = 128 threads (2 waves). Lane pair (2i,2i+1) covers query i of chunk: lane h owns dims 32h..32h+31.
__global__ __launch_bounds__(128, 4) void k_lse(const float* __restrict__ q, const int* __restrict__ idx,
                                                const int* __restrict__ sb, const float* __restrict__ rn,
                                                float* __restrict__ lse) {
    __shared__ float kt[16 * 68];  // 16 key rows per stage, stride 68
    __shared__ int   kq[16];
    __shared__ int   kb[16];
    __shared__ float kr[16];
    int c = blockIdx.x, r = blockIdx.y, b = blockIdx.z;
    size_t sbase = (size_t)(b * R_ + r) * L_;
    int tid = threadIdx.x;
    int qi = tid >> 1, h = tid & 1;
    int pos = c * 64 + qi;
    int myl = idx[sbase + pos];
    int mybk = sb[sbase + pos];
    const float* qb = q + (size_t)b * L_ * D_;
    float qv[32];
    {
        const float* qp = qb + (size_t)myl * D_ + h * 32;
        #pragma unroll
        for (int d = 0; d < 32; d += 4) {
            float4 f = *(const float4*)(qp + d);
            qv[d] = f.x; qv[d+1] = f.y; qv[d+2] = f.z; qv[d+3] = f.w;
        }
    }
    float m = -3.0e38f, sum = 0.0f;
    for (int s = 0; s < 8; ++s) {  // 8 stages of 16 keys: prev chunk (4) then current (4)
        int cbase = ((c + NB_ - 1 + (s >> 2)) & (NB_ - 1)) * 64 + (s & 3) * 16;
        __syncthreads();
        {
            int rw = tid >> 3, off = (tid & 7) * 8;
            int kl = idx[sbase + cbase + rw];
            const float* kp = qb + (size_t)kl * D_ + off;
            float* kd = &kt[rw * 68 + off];
            *(float4*)(kd)     = *(const float4*)(kp);
            *(float4*)(kd + 4) = *(const float4*)(kp + 4);
            if (tid < 16) {
                int kl2 = idx[sbase + cbase + tid];
                kq[tid] = kl2;
                kb[tid] = sb[sbase + cbase + tid];
                kr[tid] = rn[(size_t)b * L_ + kl2];
            }
        }
        __syncthreads();
        float sc[16];
        #pragma unroll 2
        for (int j = 0; j < 16; ++j) {
            const float* kpj = &kt[j * 68 + h * 32];
            float a0 = 0, a1 = 0, a2 = 0, a3 = 0;
            #pragma unroll
            for (int d = 0; d < 32; d += 4) {
                float4 kk = *(const float4*)(kpj + d);
                a0 = fmaf(qv[d],   kk.x, a0); a1 = fmaf(qv[d+1], kk.y, a1);
                a2 = fmaf(qv[d+2], kk.z, a2); a3 = fmaf(qv[d+3], kk.w, a3);
            }
            float part = (a0 + a1) + (a2 + a3);
            part += __shfl_xor(part, 1);       // merge the two half-dots
            float v = part * kr[j] * 0.125f;
            v = (kb[j] == mybk) ? v : -1.0e9f;
            if (kq[j] == myl) v = -1.0e5f;
            sc[j] = v;
        }
        float M = sc[0];
        #pragma unroll
        for (int j = 1; j < 16; ++j) M = fmaxf(M, sc[j]);
        float nm = fmaxf(m, M);
        float acc = sum * expf(m - nm);
        #pragma unroll
        for (int j = 0; j < 16; ++j) acc += expf(sc[j] - nm);
        sum = acc; m = nm;
    }
    if (h == 0) lse[sbase + pos] = m + logf(sum);
}

// ---------------- K5: softmax-over-L normalizers (max + fp64 sum) per (b,r)
__global__ __launch_bounds__(256) void k_wred(const float* __restrict__ lse, float* __restrict__ gm,
                                              float* __restrict__ gs) {
    __shared__ float  sm[4];
    __shared__ double sd[4];
    int br = blockIdx.x;
    const float* x = lse + (size_t)br * L_;
    int t = threadIdx.x;
    float mx = -3.0e38f;
    for (int i = t; i < L_; i += 256) mx = fmaxf(mx, x[i]);
    #pragma unroll
    for (int o = 32; o; o >>= 1) mx = fmaxf(mx, __shfl_down(mx, o));
    if ((t & 63) == 0) sm[t >> 6] = mx;
    __syncthreads();
    mx = fmaxf(fmaxf(sm[0], sm[1]), fmaxf(sm[2], sm[3]));
    double s = 0.0;
    for (int i = t; i < L_; i += 256) s += exp((double)x[i] - (double)mx);
    #pragma unroll
    for (int o = 32; o; o >>= 1) s += __shfl_down(s, o);
    if ((t & 63) == 0) sd[t >> 6] = s;
    __syncthreads();
    if (t == 0) { gm[br] = mx; gs[br] = (float)(1.0 / (sd[0] + sd[1] + sd[2] + sd[3])); }
}

// ---------------- K6: pass 2 — recompute scores, p·V, scale by w.
// Same lane-pair layout as k_lse. Output either via coalesced contrib store (sorted order)
// or atomicAdd fallback when ws is too small.
__global__ __launch_bounds__(128, 4) void k_att(const float* __restrict__ q, const float* __restrict__ val,
                                                const int* __restrict__ idx, const int* __restrict__ sb,
                                                const float* __restrict__ rn, const float* __restrict__ lse,
                                                const float* __restrict__ gm, const float* __restrict__ gs,
                                                float* __restrict__ out, float* __restrict__ contrib,
                                                int use_contrib) {
    __shared__ float kt[16 * 68];
    __shared__ float vt[16 * 68];
    __shared__ int   kq[16];
    __shared__ int   kb[16];
    __shared__ float kr[16];
    int c = blockIdx.x, r = blockIdx.y, b = blockIdx.z;
    size_t sbase = (size_t)(b * R_ + r) * L_;
    int tid = threadIdx.x;
    int qi = tid >> 1, h = tid & 1;
    int pos = c * 64 + qi;
    int myl = idx[sbase + pos];
    int mybk = sb[sbase + pos];
    const float* qb = q   + (size_t)b * L_ * D_;
    const float* vb = val + (size_t)b * L_ * D_;
    float qv[32];
    {
        const float* qp = qb + (size_t)myl * D_ + h * 32;
        #pragma unroll
        for (int d = 0; d < 32; d += 4) {
            float4 f = *(const float4*)(qp + d);
            qv[d] = f.x; qv[d+1] = f.y; qv[d+2] = f.z; qv[d+3] = f.w;
        }
    }
    float myLse = lse[sbase + pos];
    float acc[32];
    #pragma unroll
    for (int d = 0; d < 32; ++d) acc[d] = 0.0f;
    for (int s = 0; s < 8; ++s) {
        int cbase = ((c + NB_ - 1 + (s >> 2)) & (NB_ - 1)) * 64 + (s & 3) * 16;
        __syncthreads();
        {
            int rw = tid >> 3, off = (tid & 7) * 8;
            int kl = idx[sbase + cbase + rw];
            const float* kp = qb + (size_t)kl * D_ + off;
            const float* vp = vb + (size_t)kl * D_ + off;
            float* kd = &kt[rw * 68 + off];
            float* vd = &vt[rw * 68 + off];
            *(float4*)(kd)     = *(const float4*)(kp);
            *(float4*)(kd + 4) = *(const float4*)(kp + 4);
            *(float4*)(vd)     = *(const float4*)(vp);
            *(float4*)(vd + 4) = *(const float4*)(vp + 4);
            if (tid < 16) {
                int kl2 = idx[sbase + cbase + tid];
                kq[tid] = kl2;
                kb[tid] = sb[sbase + cbase + tid];
                kr[tid] = rn[(size_t)b * L_ + kl2];
            }
        }
        __syncthreads();
        float sc[16];
        #pragma unroll 2
        for (int j = 0; j < 16; ++j) {
            const float* kpj = &kt[j * 68 + h * 32];
            float a0 = 0, a1 = 0, a2 = 0, a3 = 0;
            #pragma unroll
            for (int d = 0; d < 32; d += 4) {
                float4 kk = *(const float4*)(kpj + d);
                a0 = fmaf(qv[d],   kk.x, a0); a1 = fmaf(qv[d+1], kk.y, a1);
                a2 = fmaf(qv[d+2], kk.z, a2); a3 = fmaf(qv[d+3], kk.w, a3);
            }
            float part = (a0 + a1) + (a2 + a3);
            part += __shfl_xor(part, 1);
            float v = part * kr[j] * 0.125f;
            v = (kb[j] == mybk) ? v : -1.0e9f;
            if (kq[j] == myl) v = -1.0e5f;
            sc[j] = expf(v - myLse);           // p (masked keys underflow to 0, as in ref)
        }
        #pragma unroll 2
        for (int j = 0; j < 16; ++j) {
            float p = sc[j];
            const float* vpj = &vt[j * 68 + h * 32];
            #pragma unroll
            for (int d = 0; d < 32; d += 4) {
                float4 vv = *(const float4*)(vpj + d);
                acc[d]   = fmaf(p, vv.x, acc[d]);   acc[d+1] = fmaf(p, vv.y, acc[d+1]);
                acc[d+2] = fmaf(p, vv.z, acc[d+2]); acc[d+3] = fmaf(p, vv.w, acc[d+3]);
            }
        }
    }
    int brr = b * R_ + r;
    float w = expf(myLse - gm[brr]) * gs[brr];
    if (use_contrib) {
        float* cp = contrib + ((size_t)brr * L_ + pos) * D_ + h * 32;
        #pragma unroll
        for (int d = 0; d < 32; d += 4) {
            float4 o;
            o.x = w * acc[d]; o.y = w * acc[d+1]; o.z = w * acc[d+2]; o.w = w * acc[d+3];
            *(float4*)(cp + d) = o;
        }
    } else {
        float* op = out + ((size_t)b * L_ + myl) * D_ + h * 32;
        #pragma unroll
        for (int d = 0; d < 32; ++d) unsafeAtomicAdd(op + d, w * acc[d]);
    }
}

// ---------------- K7: gather the 4 round contributions back to original order and sum
__global__ __launch_bounds__(256) void k_comb(const float* __restrict__ contrib, const int* __restrict__ iv,
                                              float* __restrict__ out) {
    int gid = blockIdx.x * 256 + threadIdx.x;
    int row = gid >> 2;              // b*L + l
    int ch  = (gid & 3) * 16;
    int b = row >> 13, l = row & (L_ - 1);
    float s[16];
    #pragma unroll
    for (int i = 0; i < 16; ++i) s[i] = 0.0f;
    #pragma unroll
    for (int r = 0; r < R_; ++r) {
        int brr = b * R_ + r;
        int pos = iv[(size_t)brr * L_ + l];
        const float* cp = contrib + ((size_t)brr * L_ + pos) * D_ + ch;
        #pragma unroll
        for (int i = 0; i < 16; i += 4) {
            float4 f = *(const float4*)(cp + i);
            s[i] += f.x; s[i+1] += f.y; s[i+2] += f.z; s[i+3] += f.w;
        }
    }
    float* op = out + (size_t)row * D_ + ch;
    #pragma unroll
    for (int i = 0; i < 16; i += 4) {
        float4 o; o.x = s[i]; o.y = s[i+1]; o.z = s[i+2]; o.w = s[i+3];
        *(float4*)(op + i) = o;
    }
}

// ---------------- workspace layout (bytes)
#define OFF_RMN     0u
#define OFF_RN      2097152u
#define OFF_H       2621440u
#define OFF_IDX     4718592u
#define OFF_SB      6815744u
#define OFF_LSE     8912896u
#define OFF_GM      11010048u
#define OFF_GS      11010304u
#define OFF_INV     11010560u
#define OFF_CONTRIB 13107712u
#define CONTRIB_BYTES 536870912ull   // B*R*L*D*4

extern "C" void kernel_launch(void* const* d_in, const int* in_sizes, int n_in,
                              void* d_out, int out_size, void* d_ws, size_t ws_size,
                              hipStream_t stream) {
    const float* q  = (const float*)d_in[0];
    const float* v  = (const float*)d_in[1];
    const float* rm = (const float*)d_in[2];
    float* out = (float*)d_out;
    char* ws = (char*)d_ws;
    double* rmn = (double*)(ws + OFF_RMN);
    float*  rn  = (float*)(ws + OFF_RN);
    int*    h   = (int*)(ws + OFF_H);
    int*    idx = (int*)(ws + OFF_IDX);
    int*    sb  = (int*)(ws + OFF_SB);
    float*  lse = (float*)(ws + OFF_LSE);
    float*  gm  = (float*)(ws + OFF_GM);
    float*  gs  = (float*)(ws + OFF_GS);
    int*    iv  = (int*)(ws + OFF_INV);
    float*  contrib = (float*)(ws + OFF_CONTRIB);

    int use_contrib = (ws_size >= (size_t)OFF_CONTRIB + CONTRIB_BYTES) ? 1 : 0;
    if (!use_contrib)
        hipMemsetAsync(d_out, 0, (size_t)B_ * L_ * D_ * sizeof(float), stream);
    hipLaunchKernelGGL(k_rmnorm, dim3(B_ * R_), dim3(64), 0, stream, rm, rmn);
    hipLaunchKernelGGL(k_hash, dim3(L_ / 256, R_, B_), dim3(256), 0, stream, q, rmn, rn, h);
    hipLaunchKernelGGL(k_sort, dim3(B_ * R_), dim3(64), 0, stream, h, idx, sb, iv);
    hipLaunchKernelGGL(k_lse, dim3(NB_, R_, B_), dim3(128), 0, stream, q, idx, sb, rn, lse);
    hipLaunchKernelGGL(k_wred, dim3(B_ * R_), dim3(256), 0, stream, lse, gm, gs);
    hipLaunchKernelGGL(k_att, dim3(NB_, R_, B_), dim3(128), 0, stream, q, v, idx, sb, rn, lse, gm, gs,
                       out, contrib, use_contrib);
    if (use_contrib)
        hipLaunchKernelGGL(k_comb, dim3(B_ * L_ * 4 / 256), dim3(256), 0, stream, contrib, iv, out);
}

// Round 3
// 1544.363 us; speedup vs baseline: 1.7562x; 1.7562x over previous
//
#include <hip/hip_runtime.h>
#include <math.h>

#define B_   16
#define L_   8192
#define D_   64
#define R_   4
#define NB_  128   // n_buckets = L/64
#define NH_  64    // rand_matrix last dim = n_buckets/2

// ---------------- K1: normalize rand_matrix columns over d (fp64), store [b][r][n][d]
__global__ __launch_bounds__(64) void k_rmnorm(const float* __restrict__ rm, double* __restrict__ rmn) {
    int b = blockIdx.x >> 2, r = blockIdx.x & 3;
    int n = threadIdx.x;
    float v[D_];
    double ss = 0.0;
    #pragma unroll
    for (int d = 0; d < D_; ++d) {
        float f = rm[((size_t)(b * D_ + d) * R_ + r) * NH_ + n];
        v[d] = f;
        ss += (double)f * (double)f;
    }
    double nrm = sqrt(ss); if (nrm < 1e-12) nrm = 1e-12;
    double inv = 1.0 / nrm;
    double* o = rmn + ((size_t)(b * R_ + r) * NH_ + n) * D_;
    #pragma unroll
    for (int d = 0; d < D_; ++d) o[d] = (double)v[d] * inv;
}

// ---------------- K2: LSH hash, fp64 dots (argmax over [xR,-xR]); also 1/||q||
__global__ __launch_bounds__(256) void k_hash(const float* __restrict__ q, const double* __restrict__ rmn,
                                              float* __restrict__ rn, int* __restrict__ h) {
    __shared__ double rms[NH_ * D_]; // 32 KB
    int b = blockIdx.z, r = blockIdx.y;
    int l = blockIdx.x * 256 + threadIdx.x;
    const double* src = rmn + (size_t)(b * R_ + r) * NH_ * D_;
    for (int i = threadIdx.x; i < NH_ * D_; i += 256) rms[i] = src[i];
    const float* qp = q + ((size_t)b * L_ + l) * D_;
    double qd[D_];
    double ss = 0.0;
    #pragma unroll
    for (int d = 0; d < D_; d += 4) {
        float4 f = *(const float4*)(qp + d);
        qd[d] = f.x; qd[d+1] = f.y; qd[d+2] = f.z; qd[d+3] = f.w;
        ss += (double)f.x * f.x + (double)f.y * f.y + (double)f.z * f.z + (double)f.w * f.w;
    }
    __syncthreads();
    double best = -1.0e300; int bi = 0;
    for (int n = 0; n < NH_; ++n) {
        const double* kp = &rms[n * D_];
        double a0 = 0, a1 = 0, a2 = 0, a3 = 0;
        #pragma unroll
        for (int d = 0; d < D_; d += 4) {
            a0 = fma(qd[d],   kp[d],   a0);
            a1 = fma(qd[d+1], kp[d+1], a1);
            a2 = fma(qd[d+2], kp[d+2], a2);
            a3 = fma(qd[d+3], kp[d+3], a3);
        }
        double s = (a0 + a1) + (a2 + a3);
        if (s > best)  { best = s;  bi = n; }        // +xR first (ref concat order)
        if (-s > best) { best = -s; bi = n + NH_; }  // then -xR
    }
    h[(size_t)(b * R_ + r) * L_ + l] = bi;
    if (r == 0) {
        double nrm = sqrt(ss); if (nrm < 1e-12) nrm = 1e-12;
        rn[(size_t)b * L_ + l] = (float)(1.0 / nrm);
    }
}

// ---------------- K3: stable counting sort by bucket per (b,r); 1 wave per block
//                  also emits inverse permutation iv[l] = sorted position of l
__global__ __launch_bounds__(64) void k_sort(const int* __restrict__ h, int* __restrict__ idx,
                                             int* __restrict__ sb, int* __restrict__ iv) {
    __shared__ unsigned int cnt[NB_ * 64]; // [bucket][thread], 32 KB
    int br = blockIdx.x;
    const int* hh = h + (size_t)br * L_;
    int t = threadIdx.x;
    for (int i = t; i < NB_ * 64; i += 64) cnt[i] = 0;
    __syncthreads();
    int base = t * 128;                      // each thread owns 128 consecutive l
    for (int i = 0; i < 128; ++i) { int bk = hh[base + i]; cnt[bk * 64 + t]++; }
    __syncthreads();
    int fb = t * 128;
    unsigned int local = 0;
    for (int i = 0; i < 128; ++i) local += cnt[fb + i];
    unsigned int v = local;
    #pragma unroll
    for (int off = 1; off < 64; off <<= 1) {
        unsigned int u = __shfl_up(v, off);
        if (t >= off) v += u;
    }
    unsigned int run = v - local; // exclusive base for this thread's 128 cells
    for (int i = 0; i < 128; ++i) { unsigned int c0 = cnt[fb + i]; cnt[fb + i] = run; run += c0; }
    __syncthreads();
    int* oi = idx + (size_t)br * L_;
    int* ob = sb  + (size_t)br * L_;
    int* ivp = iv + (size_t)br * L_;
    for (int i = 0; i < 128; ++i) {
        int l = base + i; int bk = hh[l];
        unsigned int pos = cnt[bk * 64 + t]++;
        oi[pos] = l; ob[pos] = bk; ivp[l] = (int)pos;
    }
}

// ---------------- K4: pass 1 — lse per sorted position.
// Block = 128 threads (2 waves). Lane pair (2i,2i+1) covers query i of chunk: lane h owns dims 32h..32h+31.
__global__ __launch_bounds__(128, 4) void k_lse(const float* __restrict__ q, const int* __restrict__ idx,
                                                const int* __restrict__ sb, const float* __restrict__ rn,
                                                float* __restrict__ lse) {
    __shared__ float kt[16 * 68];  // 16 key rows per stage, stride 68
    __shared__ int   kq[16];
    __shared__ int   kb[16];
    __shared__ float kr[16];
    int c = blockIdx.x, r = blockIdx.y, b = blockIdx.z;
    size_t sbase = (size_t)(b * R_ + r) * L_;
    int tid = threadIdx.x;
    int qi = tid >> 1, h = tid & 1;
    int pos = c * 64 + qi;
    int myl = idx[sbase + pos];
    int mybk = sb[sbase + pos];
    const float* qb = q + (size_t)b * L_ * D_;
    float qv[32];
    {
        const float* qp = qb + (size_t)myl * D_ + h * 32;
        #pragma unroll
        for (int d = 0; d < 32; d += 4) {
            float4 f = *(const float4*)(qp + d);
            qv[d] = f.x; qv[d+1] = f.y; qv[d+2] = f.z; qv[d+3] = f.w;
        }
    }
    float m = -3.0e38f, sum = 0.0f;
    for (int s = 0; s < 8; ++s) {  // 8 stages of 16 keys: prev chunk (4) then current (4)
        int cbase = ((c + NB_ - 1 + (s >> 2)) & (NB_ - 1)) * 64 + (s & 3) * 16;
        __syncthreads();
        {
            int rw = tid >> 3, off = (tid & 7) * 8;
            int kl = idx[sbase + cbase + rw];
            const float* kp = qb + (size_t)kl * D_ + off;
            float* kd = &kt[rw * 68 + off];
            *(float4*)(kd)     = *(const float4*)(kp);
            *(float4*)(kd + 4) = *(const float4*)(kp + 4);
            if (tid < 16) {
                int kl2 = idx[sbase + cbase + tid];
                kq[tid] = kl2;
                kb[tid] = sb[sbase + cbase + tid];
                kr[tid] = rn[(size_t)b * L_ + kl2];
            }
        }
        __syncthreads();
        float sc[16];
        #pragma unroll 2
        for (int j = 0; j < 16; ++j) {
            const float* kpj = &kt[j * 68 + h * 32];
            float a0 = 0, a1 = 0, a2 = 0, a3 = 0;
            #pragma unroll
            for (int d = 0; d < 32; d += 4) {
                float4 kk = *(const float4*)(kpj + d);
                a0 = fmaf(qv[d],   kk.x, a0); a1 = fmaf(qv[d+1], kk.y, a1);
                a2 = fmaf(qv[d+2], kk.z, a2); a3 = fmaf(qv[d+3], kk.w, a3);
            }
            float part = (a0 + a1) + (a2 + a3);
            part += __shfl_xor(part, 1);       // merge the two half-dots
            float v = part * kr[j] * 0.125f;
            v = (kb[j] == mybk) ? v : -1.0e9f;
            if (kq[j] == myl) v = -1.0e5f;
            sc[j] = v;
        }
        float M = sc[0];
        #pragma unroll
        for (int j = 1; j < 16; ++j) M = fmaxf(M, sc[j]);
        float nm = fmaxf(m, M);
        float acc = sum * expf(m - nm);
        #pragma unroll
        for (int j = 0; j < 16; ++j) acc += expf(sc[j] - nm);
        sum = acc; m = nm;
    }
    if (h == 0) lse[sbase + pos] = m + logf(sum);
}

// ---------------- K5: softmax-over-L normalizers (max + fp64 sum) per (b,r)
__global__ __launch_bounds__(256) void k_wred(const float* __restrict__ lse, float* __restrict__ gm,
                                              float* __restrict__ gs) {
    __shared__ float  sm[4];
    __shared__ double sd[4];
    int br = blockIdx.x;
    const float* x = lse + (size_t)br * L_;
    int t = threadIdx.x;
    float mx = -3.0e38f;
    for (int i = t; i < L_; i += 256) mx = fmaxf(mx, x[i]);
    #pragma unroll
    for (int o = 32; o; o >>= 1) mx = fmaxf(mx, __shfl_down(mx, o));
    if ((t & 63) == 0) sm[t >> 6] = mx;
    __syncthreads();
    mx = fmaxf(fmaxf(sm[0], sm[1]), fmaxf(sm[2], sm[3]));
    double s = 0.0;
    for (int i = t; i < L_; i += 256) s += exp((double)x[i] - (double)mx);
    #pragma unroll
    for (int o = 32; o; o >>= 1) s += __shfl_down(s, o);
    if ((t & 63) == 0) sd[t >> 6] = s;
    __syncthreads();
    if (t == 0) { gm[br] = mx; gs[br] = (float)(1.0 / (sd[0] + sd[1] + sd[2] + sd[3])); }
}

// ---------------- K6: pass 2 — recompute scores, p·V, scale by w.
// One launch per round r. mode=1: coalesced store into contrib[b*bstride + pos*D] (sorted order).
// mode=0: atomicAdd fallback into out (original order).
__global__ __launch_bounds__(128, 4) void k_att(const float* __restrict__ q, const float* __restrict__ val,
                                                const int* __restrict__ idx, const int* __restrict__ sb,
                                                const float* __restrict__ rn, const float* __restrict__ lse,
                                                const float* __restrict__ gm, const float* __restrict__ gs,
                                                float* __restrict__ out, float* __restrict__ contrib,
                                                long bstride, int r, int mode) {
    __shared__ float kt[16 * 68];
    __shared__ float vt[16 * 68];
    __shared__ int   kq[16];
    __shared__ int   kb[16];
    __shared__ float kr[16];
    int c = blockIdx.x, b = blockIdx.z;
    size_t sbase = (size_t)(b * R_ + r) * L_;
    int tid = threadIdx.x;
    int qi = tid >> 1, h = tid & 1;
    int pos = c * 64 + qi;
    int myl = idx[sbase + pos];
    int mybk = sb[sbase + pos];
    const float* qb = q   + (size_t)b * L_ * D_;
    const float* vb = val + (size_t)b * L_ * D_;
    float qv[32];
    {
        const float* qp = qb + (size_t)myl * D_ + h * 32;
        #pragma unroll
        for (int d = 0; d < 32; d += 4) {
            float4 f = *(const float4*)(qp + d);
            qv[d] = f.x; qv[d+1] = f.y; qv[d+2] = f.z; qv[d+3] = f.w;
        }
    }
    float myLse = lse[sbase + pos];
    float acc[32];
    #pragma unroll
    for (int d = 0; d < 32; ++d) acc[d] = 0.0f;
    for (int s = 0; s < 8; ++s) {
        int cbase = ((c + NB_ - 1 + (s >> 2)) & (NB_ - 1)) * 64 + (s & 3) * 16;
        __syncthreads();
        {
            int rw = tid >> 3, off = (tid & 7) * 8;
            int kl = idx[sbase + cbase + rw];
            const float* kp = qb + (size_t)kl * D_ + off;
            const float* vp = vb + (size_t)kl * D_ + off;
            float* kd = &kt[rw * 68 + off];
            float* vd = &vt[rw * 68 + off];
            *(float4*)(kd)     = *(const float4*)(kp);
            *(float4*)(kd + 4) = *(const float4*)(kp + 4);
            *(float4*)(vd)     = *(const float4*)(vp);
            *(float4*)(vd + 4) = *(const float4*)(vp + 4);
            if (tid < 16) {
                int kl2 = idx[sbase + cbase + tid];
                kq[tid] = kl2;
                kb[tid] = sb[sbase + cbase + tid];
                kr[tid] = rn[(size_t)b * L_ + kl2];
            }
        }
        __syncthreads();
        float sc[16];
        #pragma unroll 2
        for (int j = 0; j < 16; ++j) {
            const float* kpj = &kt[j * 68 + h * 32];
            float a0 = 0, a1 = 0, a2 = 0, a3 = 0;
            #pragma unroll
            for (int d = 0; d < 32; d += 4) {
                float4 kk = *(const float4*)(kpj + d);
                a0 = fmaf(qv[d],   kk.x, a0); a1 = fmaf(qv[d+1], kk.y, a1);
                a2 = fmaf(qv[d+2], kk.z, a2); a3 = fmaf(qv[d+3], kk.w, a3);
            }
            float part = (a0 + a1) + (a2 + a3);
            part += __shfl_xor(part, 1);
            float v = part * kr[j] * 0.125f;
            v = (kb[j] == mybk) ? v : -1.0e9f;
            if (kq[j] == myl) v = -1.0e5f;
            sc[j] = expf(v - myLse);           // p (masked keys underflow to 0, as in ref)
        }
        #pragma unroll 2
        for (int j = 0; j < 16; ++j) {
            float p = sc[j];
            const float* vpj = &vt[j * 68 + h * 32];
            #pragma unroll
            for (int d = 0; d < 32; d += 4) {
                float4 vv = *(const float4*)(vpj + d);
                acc[d]   = fmaf(p, vv.x, acc[d]);   acc[d+1] = fmaf(p, vv.y, acc[d+1]);
                acc[d+2] = fmaf(p, vv.z, acc[d+2]); acc[d+3] = fmaf(p, vv.w, acc[d+3]);
            }
        }
    }
    int brr = b * R_ + r;
    float w = expf(myLse - gm[brr]) * gs[brr];
    if (mode) {
        float* cp = contrib + (size_t)b * bstride + (size_t)pos * D_ + h * 32;
        #pragma unroll
        for (int d = 0; d < 32; d += 4) {
            float4 o;
            o.x = w * acc[d]; o.y = w * acc[d+1]; o.z = w * acc[d+2]; o.w = w * acc[d+3];
            *(float4*)(cp + d) = o;
        }
    } else {
        float* op = out + ((size_t)b * L_ + myl) * D_ + h * 32;
        #pragma unroll
        for (int d = 0; d < 32; ++d) unsafeAtomicAdd(op + d, w * acc[d]);
    }
}

// ---------------- K7a: gather all 4 round contributions (full contrib) and write out
__global__ __launch_bounds__(256) void k_comb_full(const float* __restrict__ contrib,
                                                   const int* __restrict__ iv,
                                                   float* __restrict__ out) {
    int gid = blockIdx.x * 256 + threadIdx.x;
    int row = gid >> 2;              // b*L + l
    int ch  = (gid & 3) * 16;
    int b = row >> 13, l = row & (L_ - 1);
    float s[16];
    #pragma unroll
    for (int i = 0; i < 16; ++i) s[i] = 0.0f;
    #pragma unroll
    for (int r = 0; r < R_; ++r) {
        int brr = b * R_ + r;
        int pos = iv[(size_t)brr * L_ + l];
        const float* cp = contrib + ((size_t)brr * L_ + pos) * D_ + ch;
        #pragma unroll
        for (int i = 0; i < 16; i += 4) {
            float4 f = *(const float4*)(cp + i);
            s[i] += f.x; s[i+1] += f.y; s[i+2] += f.z; s[i+3] += f.w;
        }
    }
    float* op = out + (size_t)row * D_ + ch;
    #pragma unroll
    for (int i = 0; i < 16; i += 4) {
        float4 o; o.x = s[i]; o.y = s[i+1]; o.z = s[i+2]; o.w = s[i+3];
        *(float4*)(op + i) = o;
    }
}

// ---------------- K7b: gather one round's slice contrib[b][pos] and add into out
__global__ __launch_bounds__(256) void k_comb_add(const float* __restrict__ contrib,
                                                  const int* __restrict__ iv,
                                                  float* __restrict__ out, int r) {
    int gid = blockIdx.x * 256 + threadIdx.x;
    int row = gid >> 2;              // b*L + l
    int ch  = (gid & 3) * 16;
    int b = row >> 13, l = row & (L_ - 1);
    int pos = iv[(size_t)(b * R_ + r) * L_ + l];
    const float* cp = contrib + ((size_t)b * L_ + pos) * D_ + ch;
    float* op = out + (size_t)row * D_ + ch;
    #pragma unroll
    for (int i = 0; i < 16; i += 4) {
        float4 f = *(const float4*)(cp + i);
        float4 o = *(const float4*)(op + i);
        o.x += f.x; o.y += f.y; o.z += f.z; o.w += f.w;
        *(float4*)(op + i) = o;
    }
}

// ---------------- workspace layout (bytes)
#define OFF_RMN     0u
#define OFF_RN      2097152u
#define OFF_H       2621440u
#define OFF_IDX     4718592u
#define OFF_SB      6815744u
#define OFF_LSE     8912896u
#define OFF_GM      11010048u
#define OFF_GS      11010304u
#define OFF_INV     11010560u
#define OFF_CONTRIB 13107712u
#define CONTRIB_FULL_BYTES  134217728ull   // B*R*L*D*4 = 128 MiB
#define CONTRIB_SLICE_BYTES 33554432ull    // B*L*D*4   =  32 MiB

extern "C" void kernel_launch(void* const* d_in, const int* in_sizes, int n_in,
                              void* d_out, int out_size, void* d_ws, size_t ws_size,
                              hipStream_t stream) {
    const float* q  = (const float*)d_in[0];
    const float* v  = (const float*)d_in[1];
    const float* rm = (const float*)d_in[2];
    float* out = (float*)d_out;
    char* ws = (char*)d_ws;
    double* rmn = (double*)(ws + OFF_RMN);
    float*  rn  = (float*)(ws + OFF_RN);
    int*    h   = (int*)(ws + OFF_H);
    int*    idx = (int*)(ws + OFF_IDX);
    int*    sb  = (int*)(ws + OFF_SB);
    float*  lse = (float*)(ws + OFF_LSE);
    float*  gm  = (float*)(ws + OFF_GM);
    float*  gs  = (float*)(ws + OFF_GS);
    int*    iv  = (int*)(ws + OFF_INV);
    float*  contrib = (float*)(ws + OFF_CONTRIB);

    int tierA = (ws_size >= (size_t)OFF_CONTRIB + CONTRIB_FULL_BYTES) ? 1 : 0;
    int tierB = (!tierA && ws_size >= (size_t)OFF_CONTRIB + CONTRIB_SLICE_BYTES) ? 1 : 0;

    hipLaunchKernelGGL(k_rmnorm, dim3(B_ * R_), dim3(64), 0, stream, rm, rmn);
    hipLaunchKernelGGL(k_hash, dim3(L_ / 256, R_, B_), dim3(256), 0, stream, q, rmn, rn, h);
    hipLaunchKernelGGL(k_sort, dim3(B_ * R_), dim3(64), 0, stream, h, idx, sb, iv);
    hipLaunchKernelGGL(k_lse, dim3(NB_, R_, B_), dim3(128), 0, stream, q, idx, sb, rn, lse);
    hipLaunchKernelGGL(k_wred, dim3(B_ * R_), dim3(256), 0, stream, lse, gm, gs);

    if (tierA) {
        for (int r = 0; r < R_; ++r)
            hipLaunchKernelGGL(k_att, dim3(NB_, 1, B_), dim3(128), 0, stream, q, v, idx, sb, rn,
                               lse, gm, gs, out, contrib + (size_t)r * L_ * D_,
                               (long)R_ * L_ * D_, r, 1);
        hipLaunchKernelGGL(k_comb_full, dim3(B_ * L_ * 4 / 256), dim3(256), 0, stream,
                           contrib, iv, out);
    } else if (tierB) {
        hipMemsetAsync(d_out, 0, (size_t)B_ * L_ * D_ * sizeof(float), stream);
        for (int r = 0; r < R_; ++r) {
            hipLaunchKernelGGL(k_att, dim3(NB_, 1, B_), dim3(128), 0, stream, q, v, idx, sb, rn,
                               lse, gm, gs, out, contrib, (long)L_ * D_, r, 1);
            hipLaunchKernelGGL(k_comb_add, dim3(B_ * L_ * 4 / 256), dim3(256), 0, stream,
                               contrib, iv, out, r);
        }
    } else {
        hipMemsetAsync(d_out, 0, (size_t)B_ * L_ * D_ * sizeof(float), stream);
        for (int r = 0; r < R_; ++r)
            hipLaunchKernelGGL(k_att, dim3(NB_, 1, B_), dim3(128), 0, stream, q, v, idx, sb, rn,
                               lse, gm, gs, out, contrib, 0L, r, 0);
    }
}

// Round 4
// 648.137 us; speedup vs baseline: 4.1846x; 2.3828x over previous
//
#include <hip/hip_runtime.h>
#include <math.h>

#define B_   16
#define L_   8192
#define D_   64
#define R_   4
#define NB_  128   // n_buckets = L/64
#define NH_  64    // rand_matrix last dim = n_buckets/2

// DPP helpers: quad-local (4-lane) broadcast / butterfly — pure VALU, no LDS pipe.
__device__ __forceinline__ float dpp_xor1(float x) {
    return __int_as_float(__builtin_amdgcn_mov_dpp(__float_as_int(x), 0xB1, 0xf, 0xf, true)); // quad_perm(1,0,3,2)
}
__device__ __forceinline__ float dpp_xor2(float x) {
    return __int_as_float(__builtin_amdgcn_mov_dpp(__float_as_int(x), 0x4E, 0xf, 0xf, true)); // quad_perm(2,3,0,1)
}
__device__ __forceinline__ float quad_bcast0(float x) {
    return __int_as_float(__builtin_amdgcn_mov_dpp(__float_as_int(x), 0x00, 0xf, 0xf, true)); // (0,0,0,0)
}
__device__ __forceinline__ float quad_bcast1(float x) {
    return __int_as_float(__builtin_amdgcn_mov_dpp(__float_as_int(x), 0x55, 0xf, 0xf, true)); // (1,1,1,1)
}
__device__ __forceinline__ float quad_bcast2(float x) {
    return __int_as_float(__builtin_amdgcn_mov_dpp(__float_as_int(x), 0xAA, 0xf, 0xf, true)); // (2,2,2,2)
}
__device__ __forceinline__ float quad_bcast3(float x) {
    return __int_as_float(__builtin_amdgcn_mov_dpp(__float_as_int(x), 0xFF, 0xf, 0xf, true)); // (3,3,3,3)
}

// ---------------- K1: normalize rand_matrix columns over d (fp64), store [b][r][n][d]
__global__ __launch_bounds__(64) void k_rmnorm(const float* __restrict__ rm, double* __restrict__ rmn) {
    int b = blockIdx.x >> 2, r = blockIdx.x & 3;
    int n = threadIdx.x;
    float v[D_];
    double ss = 0.0;
    #pragma unroll
    for (int d = 0; d < D_; ++d) {
        float f = rm[((size_t)(b * D_ + d) * R_ + r) * NH_ + n];
        v[d] = f;
        ss += (double)f * (double)f;
    }
    double nrm = sqrt(ss); if (nrm < 1e-12) nrm = 1e-12;
    double inv = 1.0 / nrm;
    double* o = rmn + ((size_t)(b * R_ + r) * NH_ + n) * D_;
    #pragma unroll
    for (int d = 0; d < D_; ++d) o[d] = (double)v[d] * inv;
}

// ---------------- K2: LSH hash, fp64 dots (argmax over [xR,-xR]); also 1/||q||
__global__ __launch_bounds__(256) void k_hash(const float* __restrict__ q, const double* __restrict__ rmn,
                                              float* __restrict__ rn, int* __restrict__ h) {
    __shared__ double rms[NH_ * D_]; // 32 KB
    int b = blockIdx.z, r = blockIdx.y;
    int l = blockIdx.x * 256 + threadIdx.x;
    const double* src = rmn + (size_t)(b * R_ + r) * NH_ * D_;
    for (int i = threadIdx.x; i < NH_ * D_; i += 256) rms[i] = src[i];
    const float* qp = q + ((size_t)b * L_ + l) * D_;
    double qd[D_];
    double ss = 0.0;
    #pragma unroll
    for (int d = 0; d < D_; d += 4) {
        float4 f = *(const float4*)(qp + d);
        qd[d] = f.x; qd[d+1] = f.y; qd[d+2] = f.z; qd[d+3] = f.w;
        ss += (double)f.x * f.x + (double)f.y * f.y + (double)f.z * f.z + (double)f.w * f.w;
    }
    __syncthreads();
    double best = -1.0e300; int bi = 0;
    for (int n = 0; n < NH_; ++n) {
        const double* kp = &rms[n * D_];
        double a0 = 0, a1 = 0, a2 = 0, a3 = 0;
        #pragma unroll
        for (int d = 0; d < D_; d += 4) {
            a0 = fma(qd[d],   kp[d],   a0);
            a1 = fma(qd[d+1], kp[d+1], a1);
            a2 = fma(qd[d+2], kp[d+2], a2);
            a3 = fma(qd[d+3], kp[d+3], a3);
        }
        double s = (a0 + a1) + (a2 + a3);
        if (s > best)  { best = s;  bi = n; }        // +xR first (ref concat order)
        if (-s > best) { best = -s; bi = n + NH_; }  // then -xR
    }
    h[(size_t)(b * R_ + r) * L_ + l] = bi;
    if (r == 0) {
        double nrm = sqrt(ss); if (nrm < 1e-12) nrm = 1e-12;
        rn[(size_t)b * L_ + l] = (float)(1.0 / nrm);
    }
}

// ---------------- K3: stable counting sort by bucket per (b,r); 1 wave per block
__global__ __launch_bounds__(64) void k_sort(const int* __restrict__ h, int* __restrict__ idx,
                                             int* __restrict__ sb, int* __restrict__ iv) {
    __shared__ unsigned int cnt[NB_ * 64]; // [bucket][thread], 32 KB
    int br = blockIdx.x;
    const int* hh = h + (size_t)br * L_;
    int t = threadIdx.x;
    for (int i = t; i < NB_ * 64; i += 64) cnt[i] = 0;
    __syncthreads();
    int base = t * 128;                      // each thread owns 128 consecutive l
    for (int i = 0; i < 128; ++i) { int bk = hh[base + i]; cnt[bk * 64 + t]++; }
    __syncthreads();
    int fb = t * 128;
    unsigned int local = 0;
    for (int i = 0; i < 128; ++i) local += cnt[fb + i];
    unsigned int v = local;
    #pragma unroll
    for (int off = 1; off < 64; off <<= 1) {
        unsigned int u = __shfl_up(v, off);
        if (t >= off) v += u;
    }
    unsigned int run = v - local; // exclusive base for this thread's 128 cells
    for (int i = 0; i < 128; ++i) { unsigned int c0 = cnt[fb + i]; cnt[fb + i] = run; run += c0; }
    __syncthreads();
    int* oi = idx + (size_t)br * L_;
    int* ob = sb  + (size_t)br * L_;
    int* ivp = iv + (size_t)br * L_;
    for (int i = 0; i < 128; ++i) {
        int l = base + i; int bk = hh[l];
        unsigned int pos = cnt[bk * 64 + t]++;
        oi[pos] = l; ob[pos] = bk; ivp[l] = (int)pos;
    }
}

// ---------------- K4: fused flash pass — QK^T, online softmax, PV in one sweep.
// Block = 64 threads (1 wave) = one chunk of 64 queries per (b,r).
// Quad layout: lanes (4t..4t+3) jointly own queries 4t..4t+3; lane h holds dims h*16..h*16+15
// of all 4 queries. LDS key/value rows stored as 4 slices at stride 20 words -> the quad's 4
// read addresses hit disjoint banks (conflict-free broadcast b128).
// omode: 0 = store O/sum + lse, contrib indexed [(b*R+r)*L + pos] (tierA)
//        1 = same but contrib indexed [b*L + pos] (tierB per-round slice)
//        2 = lse only (tierC pass 1)
//        3 = atomic w-weighted add into out (tierC pass 2; needs gm/gs)
__global__ __launch_bounds__(64, 2) void k_flash(const float* __restrict__ q, const float* __restrict__ val,
                                                 const int* __restrict__ idx, const int* __restrict__ sb,
                                                 const float* __restrict__ rn, float* __restrict__ lse,
                                                 const float* __restrict__ gm, const float* __restrict__ gs,
                                                 float* __restrict__ out, float* __restrict__ contrib,
                                                 int r_fixed, int omode) {
    __shared__ float kt[16 * 80];   // 16 rows x 4 slices @ stride 20 words
    __shared__ float vt[16 * 80];
    __shared__ int   kqs[16];
    __shared__ int   kbs[16];
    __shared__ float krs[16];
    int c = blockIdx.x, b = blockIdx.z;
    int r = (r_fixed < 0) ? (int)blockIdx.y : r_fixed;
    size_t sbase = (size_t)(b * R_ + r) * L_;
    int tid = threadIdx.x;
    int h = tid & 3;
    int posq = c * 64 + (tid >> 2) * 4;           // first query of this lane's quad
    int mls[4];
    #pragma unroll
    for (int qq = 0; qq < 4; ++qq) mls[qq] = idx[sbase + posq + qq];
    int ownpos  = posq + h;
    int myl_own = idx[sbase + ownpos];
    int mybk_own = sb[sbase + ownpos];
    const float* qb = q   + (size_t)b * L_ * D_;
    const float* vb = val + (size_t)b * L_ * D_;
    float qv[4][16];
    #pragma unroll
    for (int qq = 0; qq < 4; ++qq) {
        const float* qp = qb + (size_t)mls[qq] * D_ + h * 16;
        #pragma unroll
        for (int i = 0; i < 16; i += 4) {
            float4 f = *(const float4*)(qp + i);
            qv[qq][i] = f.x; qv[qq][i+1] = f.y; qv[qq][i+2] = f.z; qv[qq][i+3] = f.w;
        }
    }
    float m = -3.0e38f, sum = 0.0f;
    float acc[4][16];
    #pragma unroll
    for (int qq = 0; qq < 4; ++qq)
        #pragma unroll
        for (int i = 0; i < 16; ++i) acc[qq][i] = 0.0f;

    #pragma unroll 1
    for (int s = 0; s < 8; ++s) {   // 8 stages of 16 keys: prev chunk (4) then current (4)
        int ck = ((c + NB_ - 1 + (s >> 2)) & (NB_ - 1)) * 64 + (s & 3) * 16;
        __syncthreads();
        {
            int rw = tid >> 2, cc = tid & 3;
            int kl = idx[sbase + ck + rw];
            const float* kp = qb + (size_t)kl * D_ + cc * 16;
            float* kd = &kt[rw * 80 + cc * 20];
            #pragma unroll
            for (int i = 0; i < 16; i += 4) *(float4*)(kd + i) = *(const float4*)(kp + i);
            if (omode != 2) {
                const float* vp = vb + (size_t)kl * D_ + cc * 16;
                float* vd = &vt[rw * 80 + cc * 20];
                #pragma unroll
                for (int i = 0; i < 16; i += 4) *(float4*)(vd + i) = *(const float4*)(vp + i);
            }
            if (tid < 16) {
                int kl2 = idx[sbase + ck + tid];
                kqs[tid] = kl2;
                kbs[tid] = sb[sbase + ck + tid];
                krs[tid] = rn[(size_t)b * L_ + kl2];
            }
        }
        __syncthreads();
        float sc[16];
        #pragma unroll
        for (int j = 0; j < 16; ++j) {
            const float* kpj = &kt[j * 80 + h * 20];
            float p0 = 0, p1 = 0, p2 = 0, p3 = 0;
            #pragma unroll
            for (int i = 0; i < 16; i += 4) {
                float4 kk = *(const float4*)(kpj + i);
                p0 = fmaf(qv[0][i], kk.x, p0); p0 = fmaf(qv[0][i+1], kk.y, p0);
                p0 = fmaf(qv[0][i+2], kk.z, p0); p0 = fmaf(qv[0][i+3], kk.w, p0);
                p1 = fmaf(qv[1][i], kk.x, p1); p1 = fmaf(qv[1][i+1], kk.y, p1);
                p1 = fmaf(qv[1][i+2], kk.z, p1); p1 = fmaf(qv[1][i+3], kk.w, p1);
                p2 = fmaf(qv[2][i], kk.x, p2); p2 = fmaf(qv[2][i+1], kk.y, p2);
                p2 = fmaf(qv[2][i+2], kk.z, p2); p2 = fmaf(qv[2][i+3], kk.w, p2);
                p3 = fmaf(qv[3][i], kk.x, p3); p3 = fmaf(qv[3][i+1], kk.y, p3);
                p3 = fmaf(qv[3][i+2], kk.z, p3); p3 = fmaf(qv[3][i+3], kk.w, p3);
            }
            // 4x4 transpose-reduce across the quad: lane h ends with query h's full dot
            bool b0 = (h & 1), b1 = (h & 2) != 0;
            float u0 = b0 ? p1 : p0;
            float t0 = b0 ? p0 : p1;
            u0 += dpp_xor1(t0);
            float u2 = b0 ? p3 : p2;
            float t2 = b0 ? p2 : p3;
            u2 += dpp_xor1(t2);
            float dot = b1 ? u2 : u0;
            float t3 = b1 ? u0 : u2;
            dot += dpp_xor2(t3);
            float v2 = dot * krs[j] * 0.125f;
            v2 = (kbs[j] == mybk_own) ? v2 : -1.0e9f;   // cross-bucket mask
            if (kqs[j] == myl_own) v2 = -1.0e5f;         // self mask (overrides, as in ref)
            sc[j] = v2;
        }
        float M = sc[0];
        #pragma unroll
        for (int j = 1; j < 16; ++j) M = fmaxf(M, sc[j]);
        float mn = fmaxf(m, M);
        float alpha = expf(m - mn);
        float ps = 0.0f;
        #pragma unroll
        for (int j = 0; j < 16; ++j) { sc[j] = expf(sc[j] - mn); ps += sc[j]; }
        sum = fmaf(sum, alpha, ps);
        m = mn;
        if (omode != 2) {
            float al0 = quad_bcast0(alpha), al1 = quad_bcast1(alpha);
            float al2 = quad_bcast2(alpha), al3 = quad_bcast3(alpha);
            #pragma unroll
            for (int i = 0; i < 16; ++i) {
                acc[0][i] *= al0; acc[1][i] *= al1; acc[2][i] *= al2; acc[3][i] *= al3;
            }
            #pragma unroll
            for (int j = 0; j < 16; ++j) {
                float pq0 = quad_bcast0(sc[j]), pq1 = quad_bcast1(sc[j]);
                float pq2 = quad_bcast2(sc[j]), pq3 = quad_bcast3(sc[j]);
                const float* vpj = &vt[j * 80 + h * 20];
                #pragma unroll
                for (int i = 0; i < 16; i += 4) {
                    float4 vv = *(const float4*)(vpj + i);
                    acc[0][i]   = fmaf(pq0, vv.x, acc[0][i]);   acc[0][i+1] = fmaf(pq0, vv.y, acc[0][i+1]);
                    acc[0][i+2] = fmaf(pq0, vv.z, acc[0][i+2]); acc[0][i+3] = fmaf(pq0, vv.w, acc[0][i+3]);
                    acc[1][i]   = fmaf(pq1, vv.x, acc[1][i]);   acc[1][i+1] = fmaf(pq1, vv.y, acc[1][i+1]);
                    acc[1][i+2] = fmaf(pq1, vv.z, acc[1][i+2]); acc[1][i+3] = fmaf(pq1, vv.w, acc[1][i+3]);
                    acc[2][i]   = fmaf(pq2, vv.x, acc[2][i]);   acc[2][i+1] = fmaf(pq2, vv.y, acc[2][i+1]);
                    acc[2][i+2] = fmaf(pq2, vv.z, acc[2][i+2]); acc[2][i+3] = fmaf(pq2, vv.w, acc[2][i+3]);
                    acc[3][i]   = fmaf(pq3, vv.x, acc[3][i]);   acc[3][i+1] = fmaf(pq3, vv.y, acc[3][i+1]);
                    acc[3][i+2] = fmaf(pq3, vv.z, acc[3][i+2]); acc[3][i+3] = fmaf(pq3, vv.w, acc[3][i+3]);
                }
            }
        }
    }
    float lse_own = m + logf(sum);
    if (omode != 3) lse[sbase + ownpos] = lse_own;
    if (omode == 0 || omode == 1) {
        float s0 = quad_bcast0(sum), s1 = quad_bcast1(sum), s2 = quad_bcast2(sum), s3 = quad_bcast3(sum);
        float iv0 = 1.0f / s0, iv1 = 1.0f / s1, iv2 = 1.0f / s2, iv3 = 1.0f / s3;
        float ivs[4] = {iv0, iv1, iv2, iv3};
        float* cbase = contrib + ((omode == 0) ? (size_t)(b * R_ + r) * L_ : (size_t)b * L_) * D_;
        #pragma unroll
        for (int qq = 0; qq < 4; ++qq) {
            float* cp = cbase + (size_t)(posq + qq) * D_ + h * 16;
            #pragma unroll
            for (int i = 0; i < 16; i += 4) {
                float4 o;
                o.x = acc[qq][i] * ivs[qq];   o.y = acc[qq][i+1] * ivs[qq];
                o.z = acc[qq][i+2] * ivs[qq]; o.w = acc[qq][i+3] * ivs[qq];
                *(float4*)(cp + i) = o;
            }
        }
    } else if (omode == 3) {
        int brr = b * R_ + r;
        float gmv = gm[brr], gsv = gs[brr];
        float l0 = quad_bcast0(lse_own), l1 = quad_bcast1(lse_own);
        float l2 = quad_bcast2(lse_own), l3 = quad_bcast3(lse_own);
        float s0 = quad_bcast0(sum), s1 = quad_bcast1(sum), s2 = quad_bcast2(sum), s3 = quad_bcast3(sum);
        float ws[4];
        ws[0] = expf(l0 - gmv) * gsv / s0; ws[1] = expf(l1 - gmv) * gsv / s1;
        ws[2] = expf(l2 - gmv) * gsv / s2; ws[3] = expf(l3 - gmv) * gsv / s3;
        #pragma unroll
        for (int qq = 0; qq < 4; ++qq) {
            float* op = out + ((size_t)b * L_ + mls[qq]) * D_ + h * 16;
            #pragma unroll
            for (int i = 0; i < 16; ++i) unsafeAtomicAdd(op + i, ws[qq] * acc[qq][i]);
        }
    }
}

// ---------------- K5: softmax-over-L normalizers (max + fp64 sum) per (b,r)
// r_w < 0: grid = B*R, br = blockIdx.x. r_w >= 0: grid = B, br = blockIdx.x*R + r_w.
__global__ __launch_bounds__(256) void k_wred(const float* __restrict__ lse, float* __restrict__ gm,
                                              float* __restrict__ gs, int r_w) {
    __shared__ float  sm[4];
    __shared__ double sd[4];
    int br = (r_w < 0) ? (int)blockIdx.x : ((int)blockIdx.x * R_ + r_w);
    const float* x = lse + (size_t)br * L_;
    int t = threadIdx.x;
    float mx = -3.0e38f;
    for (int i = t; i < L_; i += 256) mx = fmaxf(mx, x[i]);
    #pragma unroll
    for (int o = 32; o; o >>= 1) mx = fmaxf(mx, __shfl_down(mx, o));
    if ((t & 63) == 0) sm[t >> 6] = mx;
    __syncthreads();
    mx = fmaxf(fmaxf(sm[0], sm[1]), fmaxf(sm[2], sm[3]));
    double s = 0.0;
    for (int i = t; i < L_; i += 256) s += exp((double)x[i] - (double)mx);
    #pragma unroll
    for (int o = 32; o; o >>= 1) s += __shfl_down(s, o);
    if ((t & 63) == 0) sd[t >> 6] = s;
    __syncthreads();
    if (t == 0) { gm[br] = mx; gs[br] = (float)(1.0 / (sd[0] + sd[1] + sd[2] + sd[3])); }
}

// ---------------- K6a: gather all 4 rounds from full contrib, apply w, write out
__global__ __launch_bounds__(256) void k_comb_full(const float* __restrict__ contrib,
                                                   const int* __restrict__ iv,
                                                   const float* __restrict__ lse,
                                                   const float* __restrict__ gm,
                                                   const float* __restrict__ gs,
                                                   float* __restrict__ out) {
    int gid = blockIdx.x * 256 + threadIdx.x;
    int row = gid >> 2;              // b*L + l
    int ch  = (gid & 3) * 16;
    int b = row >> 13, l = row & (L_ - 1);
    float s[16];
    #pragma unroll
    for (int i = 0; i < 16; ++i) s[i] = 0.0f;
    #pragma unroll
    for (int r = 0; r < R_; ++r) {
        int brr = b * R_ + r;
        int pos = iv[(size_t)brr * L_ + l];
        float w = expf(lse[(size_t)brr * L_ + pos] - gm[brr]) * gs[brr];
        const float* cp = contrib + ((size_t)brr * L_ + pos) * D_ + ch;
        #pragma unroll
        for (int i = 0; i < 16; i += 4) {
            float4 f = *(const float4*)(cp + i);
            s[i]   = fmaf(w, f.x, s[i]);   s[i+1] = fmaf(w, f.y, s[i+1]);
            s[i+2] = fmaf(w, f.z, s[i+2]); s[i+3] = fmaf(w, f.w, s[i+3]);
        }
    }
    float* op = out + (size_t)row * D_ + ch;
    #pragma unroll
    for (int i = 0; i < 16; i += 4) {
        float4 o; o.x = s[i]; o.y = s[i+1]; o.z = s[i+2]; o.w = s[i+3];
        *(float4*)(op + i) = o;
    }
}

// ---------------- K6b: gather one round's slice, apply w, accumulate into out
__global__ __launch_bounds__(256) void k_comb_add(const float* __restrict__ contrib,
                                                  const int* __restrict__ iv,
                                                  const float* __restrict__ lse,
                                                  const float* __restrict__ gm,
                                                  const float* __restrict__ gs,
                                                  float* __restrict__ out, int r) {
    int gid = blockIdx.x * 256 + threadIdx.x;
    int row = gid >> 2;              // b*L + l
    int ch  = (gid & 3) * 16;
    int b = row >> 13, l = row & (L_ - 1);
    int brr = b * R_ + r;
    int pos = iv[(size_t)brr * L_ + l];
    float w = expf(lse[(size_t)brr * L_ + pos] - gm[brr]) * gs[brr];
    const float* cp = contrib + ((size_t)b * L_ + pos) * D_ + ch;
    float* op = out + (size_t)row * D_ + ch;
    #pragma unroll
    for (int i = 0; i < 16; i += 4) {
        float4 f = *(const float4*)(cp + i);
        float4 o = *(const float4*)(op + i);
        o.x = fmaf(w, f.x, o.x); o.y = fmaf(w, f.y, o.y);
        o.z = fmaf(w, f.z, o.z); o.w = fmaf(w, f.w, o.w);
        *(float4*)(op + i) = o;
    }
}

// ---------------- workspace layout (bytes)
#define OFF_RMN     0u
#define OFF_RN      2097152u
#define OFF_H       2621440u
#define OFF_IDX     4718592u
#define OFF_SB      6815744u
#define OFF_LSE     8912896u
#define OFF_GM      11010048u
#define OFF_GS      11010304u
#define OFF_INV     11010560u
#define OFF_CONTRIB 13107712u
#define CONTRIB_FULL_BYTES  134217728ull   // B*R*L*D*4 = 128 MiB
#define CONTRIB_SLICE_BYTES 33554432ull    // B*L*D*4   =  32 MiB

extern "C" void kernel_launch(void* const* d_in, const int* in_sizes, int n_in,
                              void* d_out, int out_size, void* d_ws, size_t ws_size,
                              hipStream_t stream) {
    const float* q  = (const float*)d_in[0];
    const float* v  = (const float*)d_in[1];
    const float* rm = (const float*)d_in[2];
    float* out = (float*)d_out;
    char* ws = (char*)d_ws;
    double* rmn = (double*)(ws + OFF_RMN);
    float*  rn  = (float*)(ws + OFF_RN);
    int*    h   = (int*)(ws + OFF_H);
    int*    idx = (int*)(ws + OFF_IDX);
    int*    sb  = (int*)(ws + OFF_SB);
    float*  lse = (float*)(ws + OFF_LSE);
    float*  gm  = (float*)(ws + OFF_GM);
    float*  gs  = (float*)(ws + OFF_GS);
    int*    iv  = (int*)(ws + OFF_INV);
    float*  contrib = (float*)(ws + OFF_CONTRIB);

    int tierA = (ws_size >= (size_t)OFF_CONTRIB + CONTRIB_FULL_BYTES) ? 1 : 0;
    int tierB = (!tierA && ws_size >= (size_t)OFF_CONTRIB + CONTRIB_SLICE_BYTES) ? 1 : 0;

    hipLaunchKernelGGL(k_rmnorm, dim3(B_ * R_), dim3(64), 0, stream, rm, rmn);
    hipLaunchKernelGGL(k_hash, dim3(L_ / 256, R_, B_), dim3(256), 0, stream, q, rmn, rn, h);
    hipLaunchKernelGGL(k_sort, dim3(B_ * R_), dim3(64), 0, stream, h, idx, sb, iv);

    if (tierA) {
        hipLaunchKernelGGL(k_flash, dim3(NB_, R_, B_), dim3(64), 0, stream, q, v, idx, sb, rn,
                           lse, gm, gs, out, contrib, -1, 0);
        hipLaunchKernelGGL(k_wred, dim3(B_ * R_), dim3(256), 0, stream, lse, gm, gs, -1);
        hipLaunchKernelGGL(k_comb_full, dim3(B_ * L_ * 4 / 256), dim3(256), 0, stream,
                           contrib, iv, lse, gm, gs, out);
    } else if (tierB) {
        hipMemsetAsync(d_out, 0, (size_t)B_ * L_ * D_ * sizeof(float), stream);
        for (int r = 0; r < R_; ++r) {
            hipLaunchKernelGGL(k_flash, dim3(NB_, 1, B_), dim3(64), 0, stream, q, v, idx, sb, rn,
                               lse, gm, gs, out, contrib, r, 1);
            hipLaunchKernelGGL(k_wred, dim3(B_), dim3(256), 0, stream, lse, gm, gs, r);
            hipLaunchKernelGGL(k_comb_add, dim3(B_ * L_ * 4 / 256), dim3(256), 0, stream,
                               contrib, iv, lse, gm, gs, out, r);
        }
    } else {
        // tier C: two flash passes (lse-only, then atomic w-weighted accumulate)
        hipMemsetAsync(d_out, 0, (size_t)B_ * L_ * D_ * sizeof(float), stream);
        hipLaunchKernelGGL(k_flash, dim3(NB_, R_, B_), dim3(64), 0, stream, q, v, idx, sb, rn,
                           lse, gm, gs, out, contrib, -1, 2);
        hipLaunchKernelGGL(k_wred, dim3(B_ * R_), dim3(256), 0, stream, lse, gm, gs, -1);
        hipLaunchKernelGGL(k_flash, dim3(NB_, R_, B_), dim3(64), 0, stream, q, v, idx, sb, rn,
                           lse, gm, gs, out, contrib, -1, 3);
    }
}

// Round 5
// 617.490 us; speedup vs baseline: 4.3923x; 1.0496x over previous
//
#include <hip/hip_runtime.h>
#include <math.h>

#define B_   16
#define L_   8192
#define D_   64
#define R_   4
#define NB_  128   // n_buckets = L/64
#define NH_  64    // rand_matrix last dim = n_buckets/2

// DPP helpers: quad-local (4-lane) broadcast / butterfly — pure VALU, no LDS pipe.
__device__ __forceinline__ float dpp_xor1(float x) {
    return __int_as_float(__builtin_amdgcn_mov_dpp(__float_as_int(x), 0xB1, 0xf, 0xf, true)); // quad_perm(1,0,3,2)
}
__device__ __forceinline__ float dpp_xor2(float x) {
    return __int_as_float(__builtin_amdgcn_mov_dpp(__float_as_int(x), 0x4E, 0xf, 0xf, true)); // quad_perm(2,3,0,1)
}
__device__ __forceinline__ float quad_bcast0(float x) {
    return __int_as_float(__builtin_amdgcn_mov_dpp(__float_as_int(x), 0x00, 0xf, 0xf, true)); // (0,0,0,0)
}
__device__ __forceinline__ float quad_bcast1(float x) {
    return __int_as_float(__builtin_amdgcn_mov_dpp(__float_as_int(x), 0x55, 0xf, 0xf, true)); // (1,1,1,1)
}
__device__ __forceinline__ float quad_bcast2(float x) {
    return __int_as_float(__builtin_amdgcn_mov_dpp(__float_as_int(x), 0xAA, 0xf, 0xf, true)); // (2,2,2,2)
}
__device__ __forceinline__ float quad_bcast3(float x) {
    return __int_as_float(__builtin_amdgcn_mov_dpp(__float_as_int(x), 0xFF, 0xf, 0xf, true)); // (3,3,3,3)
}

// ---------------- K1: normalize rand_matrix columns over d (fp64), store [b][r][n][d]
__global__ __launch_bounds__(64) void k_rmnorm(const float* __restrict__ rm, double* __restrict__ rmn) {
    int b = blockIdx.x >> 2, r = blockIdx.x & 3;
    int n = threadIdx.x;
    float v[D_];
    double ss = 0.0;
    #pragma unroll
    for (int d = 0; d < D_; ++d) {
        float f = rm[((size_t)(b * D_ + d) * R_ + r) * NH_ + n];
        v[d] = f;
        ss += (double)f * (double)f;
    }
    double nrm = sqrt(ss); if (nrm < 1e-12) nrm = 1e-12;
    double inv = 1.0 / nrm;
    double* o = rmn + ((size_t)(b * R_ + r) * NH_ + n) * D_;
    #pragma unroll
    for (int d = 0; d < D_; ++d) o[d] = (double)v[d] * inv;
}

// ---------------- K2: LSH hash — fp32 argmax with top-2 margin test, fp64 re-check for
// near-tie lanes (bit-identical bucket decisions vs the all-fp64 path). Also 1/||q||.
__global__ __launch_bounds__(256) void k_hash(const float* __restrict__ q, const double* __restrict__ rmn,
                                              float* __restrict__ rn, int* __restrict__ h) {
    __shared__ double rmd[NH_ * D_]; // 32 KB
    __shared__ float  rms[NH_ * D_]; // 16 KB
    int b = blockIdx.z, r = blockIdx.y;
    int l = blockIdx.x * 256 + threadIdx.x;
    const double* src = rmn + (size_t)(b * R_ + r) * NH_ * D_;
    for (int i = threadIdx.x; i < NH_ * D_; i += 256) {
        double dv = src[i];
        rmd[i] = dv;
        rms[i] = (float)dv;
    }
    const float* qp = q + ((size_t)b * L_ + l) * D_;
    float qf[D_];
    double ss = 0.0;
    #pragma unroll
    for (int d = 0; d < D_; d += 4) {
        float4 f = *(const float4*)(qp + d);
        qf[d] = f.x; qf[d+1] = f.y; qf[d+2] = f.z; qf[d+3] = f.w;
        ss += (double)f.x * f.x + (double)f.y * f.y + (double)f.z * f.z + (double)f.w * f.w;
    }
    __syncthreads();
    float best = -1.0e30f, second = -1.0e30f; int bi = 0;
    for (int n = 0; n < NH_; ++n) {
        const float* kp = &rms[n * D_];
        float a0 = 0, a1 = 0, a2 = 0, a3 = 0;
        #pragma unroll
        for (int d = 0; d < D_; d += 4) {
            a0 = fmaf(qf[d],   kp[d],   a0);
            a1 = fmaf(qf[d+1], kp[d+1], a1);
            a2 = fmaf(qf[d+2], kp[d+2], a2);
            a3 = fmaf(qf[d+3], kp[d+3], a3);
        }
        float s = (a0 + a1) + (a2 + a3);
        if (s > best)       { second = best; best = s; bi = n; }
        else if (s > second)  second = s;
        float ns = -s;
        if (ns > best)      { second = best; best = ns; bi = n + NH_; }
        else if (ns > second) second = ns;
    }
    float qn = (float)sqrt(ss);
    if (best - second < 3.0e-5f * qn + 1.0e-7f) {
        // near-tie: redo exactly as the proven fp64 path
        double qd[D_];
        #pragma unroll
        for (int d = 0; d < D_; ++d) qd[d] = (double)qf[d];
        double bestd = -1.0e300; bi = 0;
        for (int n = 0; n < NH_; ++n) {
            const double* kp = &rmd[n * D_];
            double a0 = 0, a1 = 0, a2 = 0, a3 = 0;
            #pragma unroll
            for (int d = 0; d < D_; d += 4) {
                a0 = fma(qd[d],   kp[d],   a0);
                a1 = fma(qd[d+1], kp[d+1], a1);
                a2 = fma(qd[d+2], kp[d+2], a2);
                a3 = fma(qd[d+3], kp[d+3], a3);
            }
            double s = (a0 + a1) + (a2 + a3);
            if (s > bestd)  { bestd = s;  bi = n; }
            if (-s > bestd) { bestd = -s; bi = n + NH_; }
        }
    }
    h[(size_t)(b * R_ + r) * L_ + l] = bi;
    if (r == 0) {
        double nrm = sqrt(ss); if (nrm < 1e-12) nrm = 1e-12;
        rn[(size_t)b * L_ + l] = (float)(1.0 / nrm);
    }
}

// ---------------- K3: stable counting sort by bucket per (b,r); 1 wave per block
__global__ __launch_bounds__(64) void k_sort(const int* __restrict__ h, int* __restrict__ idx,
                                             int* __restrict__ sb, int* __restrict__ iv) {
    __shared__ unsigned int cnt[NB_ * 64]; // [bucket][thread], 32 KB
    int br = blockIdx.x;
    const int* hh = h + (size_t)br * L_;
    int t = threadIdx.x;
    for (int i = t; i < NB_ * 64; i += 64) cnt[i] = 0;
    __syncthreads();
    int base = t * 128;                      // each thread owns 128 consecutive l
    for (int i = 0; i < 128; ++i) { int bk = hh[base + i]; cnt[bk * 64 + t]++; }
    __syncthreads();
    int fb = t * 128;
    unsigned int local = 0;
    for (int i = 0; i < 128; ++i) local += cnt[fb + i];
    unsigned int v = local;
    #pragma unroll
    for (int off = 1; off < 64; off <<= 1) {
        unsigned int u = __shfl_up(v, off);
        if (t >= off) v += u;
    }
    unsigned int run = v - local; // exclusive base for this thread's 128 cells
    for (int i = 0; i < 128; ++i) { unsigned int c0 = cnt[fb + i]; cnt[fb + i] = run; run += c0; }
    __syncthreads();
    int* oi = idx + (size_t)br * L_;
    int* ob = sb  + (size_t)br * L_;
    int* ivp = iv + (size_t)br * L_;
    for (int i = 0; i < 128; ++i) {
        int l = base + i; int bk = hh[l];
        unsigned int pos = cnt[bk * 64 + t]++;
        oi[pos] = l; ob[pos] = bk; ivp[l] = (int)pos;
    }
}

// ---------------- K4: fused flash pass — QK^T, static-max softmax, PV in one sweep.
// Block = 64 threads (1 wave) = one chunk of 64 queries per (b,r).
// Quad layout: lanes (4t..4t+3) jointly own queries 4t..4t+3; lane h holds dims h*16..h*16+15
// of all 4 queries. LDS rows stored as 4 slices at stride 20 words (conflict-free broadcast b128).
// Static max: scores for query i are bounded by ||q_i||/8 = 0.125/rn — so no online rescaling.
// omode: 0 = store O/sum + lse, contrib indexed [(b*R+r)*L + pos] (tierA)
//        1 = same but contrib indexed [b*L + pos] (tierB per-round slice)
//        2 = lse only (tierC pass 1)
//        3 = atomic w-weighted add into out (tierC pass 2; needs gm/gs)
__global__ __launch_bounds__(64, 2) void k_flash(const float* __restrict__ q, const float* __restrict__ val,
                                                 const int* __restrict__ idx, const int* __restrict__ sb,
                                                 const float* __restrict__ rn, float* __restrict__ lse,
                                                 const float* __restrict__ gm, const float* __restrict__ gs,
                                                 float* __restrict__ out, float* __restrict__ contrib,
                                                 int r_fixed, int omode) {
    __shared__ float kt[16 * 80];   // 16 rows x 4 slices @ stride 20 words
    __shared__ float vt[16 * 80];
    __shared__ int   kqs[16];
    __shared__ int   kbs[16];
    __shared__ float krs[16];
    int c = blockIdx.x, b = blockIdx.z;
    int r = (r_fixed < 0) ? (int)blockIdx.y : r_fixed;
    size_t sbase = (size_t)(b * R_ + r) * L_;
    int tid = threadIdx.x;
    int h = tid & 3;
    int posq = c * 64 + (tid >> 2) * 4;           // first query of this lane's quad
    int mls[4];
    #pragma unroll
    for (int qq = 0; qq < 4; ++qq) mls[qq] = idx[sbase + posq + qq];
    int ownpos  = posq + h;
    int myl_own = idx[sbase + ownpos];
    int mybk_own = sb[sbase + ownpos];
    float m_own = 0.125f / rn[(size_t)b * L_ + myl_own];   // = ||q_own||/8, upper bound on own scores
    const float* qb = q   + (size_t)b * L_ * D_;
    const float* vb = val + (size_t)b * L_ * D_;
    float qv[4][16];
    #pragma unroll
    for (int qq = 0; qq < 4; ++qq) {
        const float* qp = qb + (size_t)mls[qq] * D_ + h * 16;
        #pragma unroll
        for (int i = 0; i < 16; i += 4) {
            float4 f = *(const float4*)(qp + i);
            qv[qq][i] = f.x; qv[qq][i+1] = f.y; qv[qq][i+2] = f.z; qv[qq][i+3] = f.w;
        }
    }
    float ps[4] = {0.0f, 0.0f, 0.0f, 0.0f};
    float acc[4][16];
    #pragma unroll
    for (int qq = 0; qq < 4; ++qq)
        #pragma unroll
        for (int i = 0; i < 16; ++i) acc[qq][i] = 0.0f;

    #pragma unroll 1
    for (int s = 0; s < 8; ++s) {   // 8 stages of 16 keys: prev chunk (4) then current (4)
        int ck = ((c + NB_ - 1 + (s >> 2)) & (NB_ - 1)) * 64 + (s & 3) * 16;
        __syncthreads();
        {
            int rw = tid >> 2, cc = tid & 3;
            int kl = idx[sbase + ck + rw];
            const float* kp = qb + (size_t)kl * D_ + cc * 16;
            float* kd = &kt[rw * 80 + cc * 20];
            #pragma unroll
            for (int i = 0; i < 16; i += 4) *(float4*)(kd + i) = *(const float4*)(kp + i);
            if (omode != 2) {
                const float* vp = vb + (size_t)kl * D_ + cc * 16;
                float* vd = &vt[rw * 80 + cc * 20];
                #pragma unroll
                for (int i = 0; i < 16; i += 4) *(float4*)(vd + i) = *(const float4*)(vp + i);
            }
            if (tid < 16) {
                int kl2 = idx[sbase + ck + tid];
                kqs[tid] = kl2;
                kbs[tid] = sb[sbase + ck + tid];
                krs[tid] = rn[(size_t)b * L_ + kl2] * 0.125f;
            }
        }
        __syncthreads();
        #pragma unroll
        for (int j = 0; j < 16; ++j) {
            const float* kpj = &kt[j * 80 + h * 20];
            float p0 = 0, p1 = 0, p2 = 0, p3 = 0;
            #pragma unroll
            for (int i = 0; i < 16; i += 4) {
                float4 kk = *(const float4*)(kpj + i);
                p0 = fmaf(qv[0][i], kk.x, p0); p0 = fmaf(qv[0][i+1], kk.y, p0);
                p0 = fmaf(qv[0][i+2], kk.z, p0); p0 = fmaf(qv[0][i+3], kk.w, p0);
                p1 = fmaf(qv[1][i], kk.x, p1); p1 = fmaf(qv[1][i+1], kk.y, p1);
                p1 = fmaf(qv[1][i+2], kk.z, p1); p1 = fmaf(qv[1][i+3], kk.w, p1);
                p2 = fmaf(qv[2][i], kk.x, p2); p2 = fmaf(qv[2][i+1], kk.y, p2);
                p2 = fmaf(qv[2][i+2], kk.z, p2); p2 = fmaf(qv[2][i+3], kk.w, p2);
                p3 = fmaf(qv[3][i], kk.x, p3); p3 = fmaf(qv[3][i+1], kk.y, p3);
                p3 = fmaf(qv[3][i+2], kk.z, p3); p3 = fmaf(qv[3][i+3], kk.w, p3);
            }
            // 4x4 transpose-reduce across the quad: lane h ends with query h's full dot
            bool b0 = (h & 1), b1 = (h & 2) != 0;
            float u0 = b0 ? p1 : p0;
            float t0 = b0 ? p0 : p1;
            u0 += dpp_xor1(t0);
            float u2 = b0 ? p3 : p2;
            float t2 = b0 ? p2 : p3;
            u2 += dpp_xor1(t2);
            float dot = b1 ? u2 : u0;
            float t3 = b1 ? u0 : u2;
            dot += dpp_xor2(t3);
            float sc = dot * krs[j];
            sc = (kbs[j] == mybk_own) ? sc : -1.0e9f;   // cross-bucket mask
            if (kqs[j] == myl_own) sc = -1.0e5f;         // self mask (overrides, as in ref)
            float p = __expf(sc - m_own);                // static max: no rescaling ever
            ps[j & 3] += p;
            if (omode != 2) {
                float pq0 = quad_bcast0(p), pq1 = quad_bcast1(p);
                float pq2 = quad_bcast2(p), pq3 = quad_bcast3(p);
                const float* vpj = &vt[j * 80 + h * 20];
                #pragma unroll
                for (int i = 0; i < 16; i += 4) {
                    float4 vv = *(const float4*)(vpj + i);
                    acc[0][i]   = fmaf(pq0, vv.x, acc[0][i]);   acc[0][i+1] = fmaf(pq0, vv.y, acc[0][i+1]);
                    acc[0][i+2] = fmaf(pq0, vv.z, acc[0][i+2]); acc[0][i+3] = fmaf(pq0, vv.w, acc[0][i+3]);
                    acc[1][i]   = fmaf(pq1, vv.x, acc[1][i]);   acc[1][i+1] = fmaf(pq1, vv.y, acc[1][i+1]);
                    acc[1][i+2] = fmaf(pq1, vv.z, acc[1][i+2]); acc[1][i+3] = fmaf(pq1, vv.w, acc[1][i+3]);
                    acc[2][i]   = fmaf(pq2, vv.x, acc[2][i]);   acc[2][i+1] = fmaf(pq2, vv.y, acc[2][i+1]);
                    acc[2][i+2] = fmaf(pq2, vv.z, acc[2][i+2]); acc[2][i+3] = fmaf(pq2, vv.w, acc[2][i+3]);
                    acc[3][i]   = fmaf(pq3, vv.x, acc[3][i]);   acc[3][i+1] = fmaf(pq3, vv.y, acc[3][i+1]);
                    acc[3][i+2] = fmaf(pq3, vv.z, acc[3][i+2]); acc[3][i+3] = fmaf(pq3, vv.w, acc[3][i+3]);
                }
            }
        }
    }
    float sum = (ps[0] + ps[1]) + (ps[2] + ps[3]);
    float lse_own, inv_own;
    if (sum > 0.0f) { lse_own = m_own + logf(sum); inv_own = 1.0f / sum; }
    else            { lse_own = -3.0e38f;          inv_own = 0.0f; }   // fully-masked row: w=0 anyway
    if (omode != 3) lse[sbase + ownpos] = lse_own;
    if (omode == 0 || omode == 1) {
        float ivs[4];
        ivs[0] = quad_bcast0(inv_own); ivs[1] = quad_bcast1(inv_own);
        ivs[2] = quad_bcast2(inv_own); ivs[3] = quad_bcast3(inv_own);
        float* cbase = contrib + ((omode == 0) ? (size_t)(b * R_ + r) * L_ : (size_t)b * L_) * D_;
        #pragma unroll
        for (int qq = 0; qq < 4; ++qq) {
            float* cp = cbase + (size_t)(posq + qq) * D_ + h * 16;
            #pragma unroll
            for (int i = 0; i < 16; i += 4) {
                float4 o;
                o.x = acc[qq][i] * ivs[qq];   o.y = acc[qq][i+1] * ivs[qq];
                o.z = acc[qq][i+2] * ivs[qq]; o.w = acc[qq][i+3] * ivs[qq];
                *(float4*)(cp + i) = o;
            }
        }
    } else if (omode == 3) {
        int brr = b * R_ + r;
        float gmv = gm[brr], gsv = gs[brr];
        float ls4[4], iv4[4];
        ls4[0] = quad_bcast0(lse_own); ls4[1] = quad_bcast1(lse_own);
        ls4[2] = quad_bcast2(lse_own); ls4[3] = quad_bcast3(lse_own);
        iv4[0] = quad_bcast0(inv_own); iv4[1] = quad_bcast1(inv_own);
        iv4[2] = quad_bcast2(inv_own); iv4[3] = quad_bcast3(inv_own);
        #pragma unroll
        for (int qq = 0; qq < 4; ++qq) {
            float w = __expf(ls4[qq] - gmv) * gsv * iv4[qq];
            float* op = out + ((size_t)b * L_ + mls[qq]) * D_ + h * 16;
            #pragma unroll
            for (int i = 0; i < 16; ++i) unsafeAtomicAdd(op + i, w * acc[qq][i]);
        }
    }
}

// ---------------- K5: softmax-over-L normalizers (max + fp64 sum) per (b,r)
__global__ __launch_bounds__(256) void k_wred(const float* __restrict__ lse, float* __restrict__ gm,
                                              float* __restrict__ gs, int r_w) {
    __shared__ float  sm[4];
    __shared__ double sd[4];
    int br = (r_w < 0) ? (int)blockIdx.x : ((int)blockIdx.x * R_ + r_w);
    const float* x = lse + (size_t)br * L_;
    int t = threadIdx.x;
    float mx = -3.0e38f;
    for (int i = t; i < L_; i += 256) mx = fmaxf(mx, x[i]);
    #pragma unroll
    for (int o = 32; o; o >>= 1) mx = fmaxf(mx, __shfl_down(mx, o));
    if ((t & 63) == 0) sm[t >> 6] = mx;
    __syncthreads();
    mx = fmaxf(fmaxf(sm[0], sm[1]), fmaxf(sm[2], sm[3]));
    double s = 0.0;
    for (int i = t; i < L_; i += 256) s += exp((double)x[i] - (double)mx);
    #pragma unroll
    for (int o = 32; o; o >>= 1) s += __shfl_down(s, o);
    if ((t & 63) == 0) sd[t >> 6] = s;
    __syncthreads();
    if (t == 0) { gm[br] = mx; gs[br] = (float)(1.0 / (sd[0] + sd[1] + sd[2] + sd[3])); }
}

// ---------------- K6a: gather all 4 rounds from full contrib, apply w, write out
__global__ __launch_bounds__(256) void k_comb_full(const float* __restrict__ contrib,
                                                   const int* __restrict__ iv,
                                                   const float* __restrict__ lse,
                                                   const float* __restrict__ gm,
                                                   const float* __restrict__ gs,
                                                   float* __restrict__ out) {
    int gid = blockIdx.x * 256 + threadIdx.x;
    int row = gid >> 2;              // b*L + l
    int ch  = (gid & 3) * 16;
    int b = row >> 13, l = row & (L_ - 1);
    float s[16];
    #pragma unroll
    for (int i = 0; i < 16; ++i) s[i] = 0.0f;
    #pragma unroll
    for (int r = 0; r < R_; ++r) {
        int brr = b * R_ + r;
        int pos = iv[(size_t)brr * L_ + l];
        float w = expf(lse[(size_t)brr * L_ + pos] - gm[brr]) * gs[brr];
        const float* cp = contrib + ((size_t)brr * L_ + pos) * D_ + ch;
        #pragma unroll
        for (int i = 0; i < 16; i += 4) {
            float4 f = *(const float4*)(cp + i);
            s[i]   = fmaf(w, f.x, s[i]);   s[i+1] = fmaf(w, f.y, s[i+1]);
            s[i+2] = fmaf(w, f.z, s[i+2]); s[i+3] = fmaf(w, f.w, s[i+3]);
        }
    }
    float* op = out + (size_t)row * D_ + ch;
    #pragma unroll
    for (int i = 0; i < 16; i += 4) {
        float4 o; o.x = s[i]; o.y = s[i+1]; o.z = s[i+2]; o.w = s[i+3];
        *(float4*)(op + i) = o;
    }
}

// ---------------- K6b: gather one round's slice, apply w, accumulate into out
__global__ __launch_bounds__(256) void k_comb_add(const float* __restrict__ contrib,
                                                  const int* __restrict__ iv,
                                                  const float* __restrict__ lse,
                                                  const float* __restrict__ gm,
                                                  const float* __restrict__ gs,
                                                  float* __restrict__ out, int r) {
    int gid = blockIdx.x * 256 + threadIdx.x;
    int row = gid >> 2;              // b*L + l
    int ch  = (gid & 3) * 16;
    int b = row >> 13, l = row & (L_ - 1);
    int brr = b * R_ + r;
    int pos = iv[(size_t)brr * L_ + l];
    float w = expf(lse[(size_t)brr * L_ + pos] - gm[brr]) * gs[brr];
    const float* cp = contrib + ((size_t)b * L_ + pos) * D_ + ch;
    float* op = out + (size_t)row * D_ + ch;
    #pragma unroll
    for (int i = 0; i < 16; i += 4) {
        float4 f = *(const float4*)(cp + i);
        float4 o = *(const float4*)(op + i);
        o.x = fmaf(w, f.x, o.x); o.y = fmaf(w, f.y, o.y);
        o.z = fmaf(w, f.z, o.z); o.w = fmaf(w, f.w, o.w);
        *(float4*)(op + i) = o;
    }
}

// ---------------- workspace layout (bytes)
#define OFF_RMN     0u
#define OFF_RN      2097152u
#define OFF_H       2621440u
#define OFF_IDX     4718592u
#define OFF_SB      6815744u
#define OFF_LSE     8912896u
#define OFF_GM      11010048u
#define OFF_GS      11010304u
#define OFF_INV     11010560u
#define OFF_CONTRIB 13107712u
#define CONTRIB_FULL_BYTES  134217728ull   // B*R*L*D*4 = 128 MiB
#define CONTRIB_SLICE_BYTES 33554432ull    // B*L*D*4   =  32 MiB

extern "C" void kernel_launch(void* const* d_in, const int* in_sizes, int n_in,
                              void* d_out, int out_size, void* d_ws, size_t ws_size,
                              hipStream_t stream) {
    const float* q  = (const float*)d_in[0];
    const float* v  = (const float*)d_in[1];
    const float* rm = (const float*)d_in[2];
    float* out = (float*)d_out;
    char* ws = (char*)d_ws;
    double* rmn = (double*)(ws + OFF_RMN);
    float*  rn  = (float*)(ws + OFF_RN);
    int*    h   = (int*)(ws + OFF_H);
    int*    idx = (int*)(ws + OFF_IDX);
    int*    sb  = (int*)(ws + OFF_SB);
    float*  lse = (float*)(ws + OFF_LSE);
    float*  gm  = (float*)(ws + OFF_GM);
    float*  gs  = (float*)(ws + OFF_GS);
    int*    iv  = (int*)(ws + OFF_INV);
    float*  contrib = (float*)(ws + OFF_CONTRIB);

    int tierA = (ws_size >= (size_t)OFF_CONTRIB + CONTRIB_FULL_BYTES) ? 1 : 0;
    int tierB = (!tierA && ws_size >= (size_t)OFF_CONTRIB + CONTRIB_SLICE_BYTES) ? 1 : 0;

    hipLaunchKernelGGL(k_rmnorm, dim3(B_ * R_), dim3(64), 0, stream, rm, rmn);
    hipLaunchKernelGGL(k_hash, dim3(L_ / 256, R_, B_), dim3(256), 0, stream, q, rmn, rn, h);
    hipLaunchKernelGGL(k_sort, dim3(B_ * R_), dim3(64), 0, stream, h, idx, sb, iv);

    if (tierA) {
        hipLaunchKernelGGL(k_flash, dim3(NB_, R_, B_), dim3(64), 0, stream, q, v, idx, sb, rn,
                           lse, gm, gs, out, contrib, -1, 0);
        hipLaunchKernelGGL(k_wred, dim3(B_ * R_), dim3(256), 0, stream, lse, gm, gs, -1);
        hipLaunchKernelGGL(k_comb_full, dim3(B_ * L_ * 4 / 256), dim3(256), 0, stream,
                           contrib, iv, lse, gm, gs, out);
    } else if (tierB) {
        hipMemsetAsync(d_out, 0, (size_t)B_ * L_ * D_ * sizeof(float), stream);
        for (int r = 0; r < R_; ++r) {
            hipLaunchKernelGGL(k_flash, dim3(NB_, 1, B_), dim3(64), 0, stream, q, v, idx, sb, rn,
                               lse, gm, gs, out, contrib, r, 1);
            hipLaunchKernelGGL(k_wred, dim3(B_), dim3(256), 0, stream, lse, gm, gs, r);
            hipLaunchKernelGGL(k_comb_add, dim3(B_ * L_ * 4 / 256), dim3(256), 0, stream,
                               contrib, iv, lse, gm, gs, out, r);
        }
    } else {
        // tier C: two flash passes (lse-only, then atomic w-weighted accumulate)
        hipMemsetAsync(d_out, 0, (size_t)B_ * L_ * D_ * sizeof(float), stream);
        hipLaunchKernelGGL(k_flash, dim3(NB_, R_, B_), dim3(64), 0, stream, q, v, idx, sb, rn,
                           lse, gm, gs, out, contrib, -1, 2);
        hipLaunchKernelGGL(k_wred, dim3(B_ * R_), dim3(256), 0, stream, lse, gm, gs, -1);
        hipLaunchKernelGGL(k_flash, dim3(NB_, R_, B_), dim3(64), 0, stream, q, v, idx, sb, rn,
                           lse, gm, gs, out, contrib, -1, 3);
    }
}